// Round 1
// 724.739 us; speedup vs baseline: 1.1060x; 1.1060x over previous
//
#include <hip/hip_runtime.h>
#include <hip/hip_bf16.h>

// Problem constants (B=16384, H=1024 fixed by the reference).
#define B_ROWS 16384
#define HDIM   1024
#define KDIM   2048   // 2*H  (d_t || h_prev along K)
#define NDIM   5120   // 5*H  (gates i,f,o,c,g along N)

typedef __attribute__((ext_vector_type(8))) __bf16 bf16x8;
typedef __attribute__((ext_vector_type(4))) float  f32x4;

// ---- workspace layout (all 256B aligned) ----
// [0,            67108864)   A packed bf16 [16384][2048]
// [67108864,     88080384)   B packed bf16 [5120][2048]   (B^T layout: [n][k])
// [88080384,     88100864)   bias fp32 [5120]
// [88100864,    255873024)   P = activated gates bf16 [16384][5120]
#define WS_OFF_B    67108864UL
#define WS_OFF_BIAS 88080384UL
#define WS_OFF_P    88100864UL

__device__ __forceinline__ void async16(const void* g, void* l) {
  __builtin_amdgcn_global_load_lds(
      (__attribute__((address_space(1))) void*)(g),
      (__attribute__((address_space(3))) void*)(l), 16, 0, 0);
}

__device__ __forceinline__ float fast_sigmoid(float x) {
  return 1.0f / (1.0f + __expf(-x));
}
__device__ __forceinline__ float fast_tanh(float x) {
  // 1 - 2/(e^{2x}+1); saturates correctly at +-1 for |x| large.
  return 1.0f - 2.0f / (__expf(2.0f * x) + 1.0f);
}

struct GatePtrs {
  const float* W[5];
  const float* U[5];
  const float* b[5];
};

// ---------- phase 1: fp32 -> bf16 packing ----------
// A[r][c] = c<1024 ? d_t[r][c] : h_prev[r][c-1024]
__global__ __launch_bounds__(256) void pack_A(const float* __restrict__ d,
                                              const float* __restrict__ h,
                                              __bf16* __restrict__ A) {
  const int idx = blockIdx.x * 256 + threadIdx.x;
  const size_t flat = (size_t)idx * 8;
  const int r = (int)(flat >> 11);
  const int c = (int)(flat & 2047);
  const float* src = (c < HDIM) ? (d + (size_t)r * HDIM + c)
                                : (h + (size_t)r * HDIM + (c - HDIM));
  const float4 v0 = ((const float4*)src)[0];
  const float4 v1 = ((const float4*)src)[1];
  bf16x8 o;
  o[0] = (__bf16)v0.x; o[1] = (__bf16)v0.y; o[2] = (__bf16)v0.z; o[3] = (__bf16)v0.w;
  o[4] = (__bf16)v1.x; o[5] = (__bf16)v1.y; o[6] = (__bf16)v1.z; o[7] = (__bf16)v1.w;
  *(bf16x8*)(A + flat) = o;
}

// Bm[row][c]: gate g = row>>10, out oo = row&1023; c<1024 -> W_g[oo][c], else U_g[oo][c-1024]
__global__ __launch_bounds__(256) void pack_B(GatePtrs gp, __bf16* __restrict__ Bm) {
  const int idx = blockIdx.x * 256 + threadIdx.x;
  const size_t flat = (size_t)idx * 8;
  const int row = (int)(flat >> 11);  // block-uniform (2048 elems = 1 row per block)
  const int c = (int)(flat & 2047);
  const int g = row >> 10;
  const int oo = row & 1023;
  const float* base = (c < HDIM) ? gp.W[g] : gp.U[g];
  const float* src = base + (size_t)oo * HDIM + (c & 1023);
  const float4 v0 = ((const float4*)src)[0];
  const float4 v1 = ((const float4*)src)[1];
  bf16x8 o;
  o[0] = (__bf16)v0.x; o[1] = (__bf16)v0.y; o[2] = (__bf16)v0.z; o[3] = (__bf16)v0.w;
  o[4] = (__bf16)v1.x; o[5] = (__bf16)v1.y; o[6] = (__bf16)v1.z; o[7] = (__bf16)v1.w;
  *(bf16x8*)(Bm + flat) = o;
}

__global__ __launch_bounds__(256) void pack_bias(GatePtrs gp, float* __restrict__ bias) {
  const int i = blockIdx.x * 256 + threadIdx.x;  // 0..5119
  bias[i] = gp.b[i >> 10][i & 1023];
}

// ---------- phase 2: fused GEMM + bias + activation ----------
// C[m][n] = act( sum_k A[m][k]*Bm[n][k] + bias[n] ), act = tanh for gate 3 else sigmoid.
//
// 256x256 tile, BK=32, 8 waves (2M x 4N, 512 thr), per-wave 128x64 output,
// 16x16x32 bf16 MFMA, acc[8][4] f32x4.
//
// Deep pipeline (T3+T4+T5 from the technique catalog):
//  - LDS is a 4-deep ring of (A 256x32 + B 256x32) bf16 tiles = 128 KiB.
//    Tile k lives in buf k&3; staged 3 tiles ahead of consumption.
//  - 2 phases per tile, 16 independent MFMA each, raw s_barrier (no
//    __syncthreads -> no vmcnt(0) drain), explicit lgkmcnt(0), setprio(1)
//    around the MFMA cluster.
//  - Each phase issues 2 global_load_lds_dwordx4 (A-half at s=0, B-half at
//    s=1) for tile k+3. Steady-state wait at each tile boundary is
//    s_waitcnt vmcnt(8): tile k+1's 4 loads were issued 4 phases ago and 8
//    newer loads stay in flight across the barrier. Tail steps 8->4->0.
//  - WAR safety: staging into buf (k+3)&3 == buf (k-1)&3 is issued only
//    after phase (k-1,1)'s ds_reads were lgkm-drained and barriered.
//    RAW safety: every wave executes its vmcnt wait BEFORE the barrier that
//    precedes the first ds_read of the new tile.
//
// LDS swizzle: row stride is 64 B (4 x 16 B chunks). Un-swizzled, an 8-lane
// issue group hits only 2 of 8 16B-granules (4-way). Chunk ^= (row>>1)&3
// makes each 8-lane group a full permutation of the 8 granules ->
// conflict-free. gload_lds forces a linear LDS dest, so the permutation is
// applied to the *global source* address (bijective per row; read side
// applies the same XOR: cOff = (quad ^ ((lr>>1)&3)) * 8 elems).
__global__ __launch_bounds__(512, 2) void gemm_act(const __bf16* __restrict__ A,
                                                   const __bf16* __restrict__ Bm,
                                                   const float* __restrict__ bias,
                                                   __bf16* __restrict__ P) {
  __shared__ __align__(16) __bf16 As[4][256 * 32];
  __shared__ __align__(16) __bf16 Bs[4][256 * 32];

  const int tid  = threadIdx.x;
  const int lane = tid & 63;
  const int wave = tid >> 6;       // 0..7
  const int quad = lane >> 4;      // 0..3
  const int lr   = lane & 15;      // row-in-16 (A/m), col-in-16 (B/n, C col)
  const int wr   = wave >> 2;      // 0..1  -> row-half of 256
  const int wc   = wave & 3;       // 0..3  -> 64-col slice
  const int cOff = ((quad ^ ((lr >> 1) & 3)) << 3);  // swizzled chunk elem offset

  // Bijective XCD swizzle: nwg = 1280 = 8*160. Within an XCD, consecutive
  // blocks walk tile_m at fixed tile_n -> the ~2.5 B-panels per XCD
  // (2.5 MB) become L2-resident.
  const int nb  = blockIdx.x;
  const int sw  = (nb & 7) * 160 + (nb >> 3);
  const int tm  = sw & 63;          // 64 row tiles
  const int tn  = sw >> 6;          // 20 col tiles
  const int row0 = tm << 8;
  const int col0 = tn << 8;

  // Per-thread staging: 2 A chunks + 2 B chunks per tile (chunk = 16 B).
  // LDS slot c -> (row c>>2, slot c&3); source chunk = (c&3) ^ ((c>>3)&3).
  const int c0 = tid, c1 = 512 + tid;
  const __bf16* srcA0 = A  + (size_t)(row0 + (c0 >> 2)) * KDIM + (((c0 & 3) ^ ((c0 >> 3) & 3)) << 3);
  const __bf16* srcA1 = A  + (size_t)(row0 + (c1 >> 2)) * KDIM + (((c1 & 3) ^ ((c1 >> 3) & 3)) << 3);
  const __bf16* srcB0 = Bm + (size_t)(col0 + (c0 >> 2)) * KDIM + (((c0 & 3) ^ ((c0 >> 3) & 3)) << 3);
  const __bf16* srcB1 = Bm + (size_t)(col0 + (c1 >> 2)) * KDIM + (((c1 & 3) ^ ((c1 >> 3) & 3)) << 3);

  f32x4 acc[8][4] = {};

  // Prologue: stage tiles 0,1,2 (12 loads/thread), wait oldest 4 (tile 0).
  for (int kp = 0; kp < 3; ++kp) {
    __bf16* da = As[kp];
    __bf16* db = Bs[kp];
    async16(srcA0 + kp * 32, da + (size_t)c0 * 8);
    async16(srcA1 + kp * 32, da + (size_t)c1 * 8);
    async16(srcB0 + kp * 32, db + (size_t)c0 * 8);
    async16(srcB1 + kp * 32, db + (size_t)c1 * 8);
  }
  asm volatile("s_waitcnt vmcnt(8)" ::: "memory");
  asm volatile("s_barrier" ::: "memory");

  const int NT = KDIM / 32;  // 64 K-tiles
  for (int k = 0; k < NT; ++k) {
    const __bf16* ab = As[k & 3];
    const __bf16* bb = Bs[k & 3];
    const int kp = k + 3;
    bf16x8 bf[4];
#pragma unroll
    for (int s = 0; s < 2; ++s) {
      bf16x8 af[4];
      if (s == 0) {
#pragma unroll
        for (int j = 0; j < 4; ++j)
          bf[j] = *(const bf16x8*)(bb + (wc * 64 + j * 16 + lr) * 32 + cOff);
      }
#pragma unroll
      for (int i = 0; i < 4; ++i)
        af[i] = *(const bf16x8*)(ab + (wr * 128 + (s * 4 + i) * 16 + lr) * 32 + cOff);

      if (kp < NT) {  // prefetch tile k+3 into buf (k-1)&3 (freed last phase)
        if (s == 0) {
          async16(srcA0 + kp * 32, As[kp & 3] + (size_t)c0 * 8);
          async16(srcA1 + kp * 32, As[kp & 3] + (size_t)c1 * 8);
        } else {
          async16(srcB0 + kp * 32, Bs[kp & 3] + (size_t)c0 * 8);
          async16(srcB1 + kp * 32, Bs[kp & 3] + (size_t)c1 * 8);
        }
      }

      asm volatile("s_barrier" ::: "memory");
      asm volatile("s_waitcnt lgkmcnt(0)" ::: "memory");
      __builtin_amdgcn_s_setprio(1);
#pragma unroll
      for (int i = 0; i < 4; ++i)
#pragma unroll
        for (int j = 0; j < 4; ++j)
          acc[s * 4 + i][j] =
              __builtin_amdgcn_mfma_f32_16x16x32_bf16(af[i], bf[j], acc[s * 4 + i][j], 0, 0, 0);
      __builtin_amdgcn_s_setprio(0);

      if (s == 1) {
        // Tile-boundary wait: ensure tile k+1's loads landed; keep newer
        // loads in flight (never vmcnt(0) until the tail).
        if (k < NT - 3)       { asm volatile("s_waitcnt vmcnt(8)" ::: "memory"); }
        else if (k == NT - 3) { asm volatile("s_waitcnt vmcnt(4)" ::: "memory"); }
        else if (k == NT - 2) { asm volatile("s_waitcnt vmcnt(0)" ::: "memory"); }
      }
      asm volatile("s_barrier" ::: "memory");
    }
  }

  // Epilogue. C/D layout (m89/m91 verified): col = lane&15, row = quad*4 + reg.
  const int gate = col0 >> 10;  // 256-col tile never crosses a gate boundary
#pragma unroll
  for (int i = 0; i < 8; ++i) {
    const int grow = row0 + wr * 128 + i * 16 + quad * 4;
#pragma unroll
    for (int j = 0; j < 4; ++j) {
      const int gcol = col0 + wc * 64 + j * 16 + lr;
      const float bv = bias[gcol];
#pragma unroll
      for (int r = 0; r < 4; ++r) {
        const float v = acc[i][j][r] + bv;
        const float a = (gate == 3) ? fast_tanh(v) : fast_sigmoid(v);
        P[(size_t)(grow + r) * NDIM + gcol] = (__bf16)a;
      }
    }
  }
}

// ---------- phase 3: cell update + per-row fraction + outputs ----------
// one block per row; 256 threads x 4 cols each
__global__ __launch_bounds__(256) void fuse_out(const __bf16* __restrict__ P,
                                                const float* __restrict__ cprev,
                                                float* __restrict__ h_out,
                                                float* __restrict__ c_out) {
  const int r = blockIdx.x;
  const int t = threadIdx.x;
  const __bf16* Pr = P + (size_t)r * NDIM;
  const float* cpr = cprev + (size_t)r * HDIM;

  float ct[4], cp[4], ov[4], gv[4];
  float num = 0.f, den = 0.f;
#pragma unroll
  for (int q = 0; q < 4; ++q) {
    const int c = t + q * 256;
    const float iv = (float)Pr[c];
    const float fv = (float)Pr[HDIM + c];
    ov[q] = (float)Pr[2 * HDIM + c];
    const float ch = (float)Pr[3 * HDIM + c];
    gv[q] = (float)Pr[4 * HDIM + c];
    cp[q] = cpr[c];
    ct[q] = iv * ch + fv * cp[q];
    num += ct[q] * cp[q];
    den += cp[q] * cp[q];
  }
  // wave (64-lane) shuffle reduce, then cross-wave via LDS
#pragma unroll
  for (int off = 32; off > 0; off >>= 1) {
    num += __shfl_down(num, off);
    den += __shfl_down(den, off);
  }
  __shared__ float sn[4], sd[4];
  const int lane = t & 63, wave = t >> 6;
  if (lane == 0) { sn[wave] = num; sd[wave] = den; }
  __syncthreads();
  const float frac = (sn[0] + sn[1] + sn[2] + sn[3]) /
                     (sd[0] + sd[1] + sd[2] + sd[3]);
#pragma unroll
  for (int q = 0; q < 4; ++q) {
    const int c = t + q * 256;
    const float cd = ct[q] - gv[q] * frac * cp[q];
    h_out[(size_t)r * HDIM + c] = ov[q] * fast_tanh(cd);
    c_out[(size_t)r * HDIM + c] = ct[q];
  }
}

extern "C" void kernel_launch(void* const* d_in, const int* in_sizes, int n_in,
                              void* d_out, int out_size, void* d_ws, size_t ws_size,
                              hipStream_t stream) {
  const float* d_t    = (const float*)d_in[0];
  const float* h_prev = (const float*)d_in[1];
  const float* c_prev = (const float*)d_in[2];
  GatePtrs gp;
  for (int g = 0; g < 5; ++g) {
    gp.W[g] = (const float*)d_in[3 + g * 3];
    gp.b[g] = (const float*)d_in[4 + g * 3];
    gp.U[g] = (const float*)d_in[5 + g * 3];
  }

  char* ws = (char*)d_ws;
  __bf16* Apack  = (__bf16*)ws;
  __bf16* Bpack  = (__bf16*)(ws + WS_OFF_B);
  float*  biasA  = (float*)(ws + WS_OFF_BIAS);
  __bf16* P      = (__bf16*)(ws + WS_OFF_P);

  float* h_out = (float*)d_out;
  float* c_out = h_out + (size_t)B_ROWS * HDIM;

  pack_A<<<dim3(B_ROWS * (KDIM / 2048)), 256, 0, stream>>>(d_t, h_prev, Apack);           // 16384 blocks
  pack_B<<<dim3(NDIM), 256, 0, stream>>>(gp, Bpack);                                      // 5120 blocks
  pack_bias<<<dim3(NDIM / 256), 256, 0, stream>>>(gp, biasA);                             // 20 blocks
  gemm_act<<<dim3((B_ROWS / 256) * (NDIM / 256)), 512, 0, stream>>>(Apack, Bpack, biasA, P); // 1280 blocks
  fuse_out<<<dim3(B_ROWS), 256, 0, stream>>>(P, c_prev, h_out, c_out);                    // 16384 blocks
}

// Round 4
// 708.838 us; speedup vs baseline: 1.1309x; 1.0224x over previous
//
#include <hip/hip_runtime.h>
#include <hip/hip_bf16.h>

// Problem constants (B=16384, H=1024 fixed by the reference).
#define B_ROWS 16384
#define HDIM   1024
#define KDIM   2048   // 2*H  (d_t || h_prev along K)
#define NDIM   5120   // 5*H  (gates i,f,o,c,g along N)

typedef __attribute__((ext_vector_type(8))) __bf16 bf16x8;
typedef __attribute__((ext_vector_type(4))) __bf16 bf16x4;
typedef __attribute__((ext_vector_type(4))) float  f32x4;

// ---- workspace layout (all 256B aligned) ----
// [0,            67108864)   A packed bf16 [16384][2048]
// [67108864,     88080384)   B packed bf16 [5120][2048]   (B^T layout: [n][k])
// [88080384,     88100864)   bias fp32 [5120]
// [88100864,    255873024)   P = activated gates bf16 [16384][5120]
#define WS_OFF_B    67108864UL
#define WS_OFF_BIAS 88080384UL
#define WS_OFF_P    88100864UL

__device__ __forceinline__ void async16(const void* g, void* l) {
  __builtin_amdgcn_global_load_lds(
      (__attribute__((address_space(1))) void*)(g),
      (__attribute__((address_space(3))) void*)(l), 16, 0, 0);
}

__device__ __forceinline__ float fast_sigmoid(float x) {
  return 1.0f / (1.0f + __expf(-x));
}
__device__ __forceinline__ float fast_tanh(float x) {
  // 1 - 2/(e^{2x}+1); saturates correctly at +-1 for |x| large.
  return 1.0f - 2.0f / (__expf(2.0f * x) + 1.0f);
}

struct GatePtrs {
  const float* W[5];
  const float* U[5];
  const float* b[5];
};

// ---------- phase 1: fp32 -> bf16 packing ----------
// A[r][c] = c<1024 ? d_t[r][c] : h_prev[r][c-1024]
__global__ __launch_bounds__(256) void pack_A(const float* __restrict__ d,
                                              const float* __restrict__ h,
                                              __bf16* __restrict__ A) {
  const int idx = blockIdx.x * 256 + threadIdx.x;
  const size_t flat = (size_t)idx * 8;
  const int r = (int)(flat >> 11);
  const int c = (int)(flat & 2047);
  const float* src = (c < HDIM) ? (d + (size_t)r * HDIM + c)
                                : (h + (size_t)r * HDIM + (c - HDIM));
  const float4 v0 = ((const float4*)src)[0];
  const float4 v1 = ((const float4*)src)[1];
  bf16x8 o;
  o[0] = (__bf16)v0.x; o[1] = (__bf16)v0.y; o[2] = (__bf16)v0.z; o[3] = (__bf16)v0.w;
  o[4] = (__bf16)v1.x; o[5] = (__bf16)v1.y; o[6] = (__bf16)v1.z; o[7] = (__bf16)v1.w;
  *(bf16x8*)(A + flat) = o;
}

// Bm[row][c]: gate g = row>>10, out oo = row&1023; c<1024 -> W_g[oo][c], else U_g[oo][c-1024]
__global__ __launch_bounds__(256) void pack_B(GatePtrs gp, __bf16* __restrict__ Bm) {
  const int idx = blockIdx.x * 256 + threadIdx.x;
  const size_t flat = (size_t)idx * 8;
  const int row = (int)(flat >> 11);  // block-uniform (2048 elems = 1 row per block)
  const int c = (int)(flat & 2047);
  const int g = row >> 10;
  const int oo = row & 1023;
  const float* base = (c < HDIM) ? gp.W[g] : gp.U[g];
  const float* src = base + (size_t)oo * HDIM + (c & 1023);
  const float4 v0 = ((const float4*)src)[0];
  const float4 v1 = ((const float4*)src)[1];
  bf16x8 o;
  o[0] = (__bf16)v0.x; o[1] = (__bf16)v0.y; o[2] = (__bf16)v0.z; o[3] = (__bf16)v0.w;
  o[4] = (__bf16)v1.x; o[5] = (__bf16)v1.y; o[6] = (__bf16)v1.z; o[7] = (__bf16)v1.w;
  *(bf16x8*)(Bm + flat) = o;
}

__global__ __launch_bounds__(256) void pack_bias(GatePtrs gp, float* __restrict__ bias) {
  const int i = blockIdx.x * 256 + threadIdx.x;  // 0..5119
  bias[i] = gp.b[i >> 10][i & 1023];
}

// ---------- phase 2: fused GEMM + bias + activation ----------
// C[m][n] = act( sum_k A[m][k]*Bm[n][k] + bias[n] ), act = tanh for gate 3 else sigmoid.
//
// 128x256 tile, BK=32, 8 waves (2M x 4N, 512 thr), per-wave 64x64 output,
// 16x16x32 bf16 MFMA, acc[4][4] f32x4.
//
// Register arithmetic (the round-2 bug): 256x256 needed acc[8][4] = 128
// regs + ~50 operands -> ~220/lane, so 2 blocks/CU (<=128/lane) was
// infeasible and launch_bounds(512,4) would force acc spills. This tile
// carries acc 64 + af/bf 32 + ~3 base ptrs ~= 115/lane -> (512,4) is an
// honest promise: 2 blocks/CU, 16 waves/CU. The co-resident block's waves
// are unsynchronized and fill this block's barrier/lgkm gaps (m114).
// Per-CU per block-K-tile: MFMA 621 cyc vs LDS-read 512 cyc -> MFMA-bound.
//
// Pipeline per K-tile k (single phase, 16 MFMA):
//   ds_read af[4]+bf[4] (8 x b128); issue 3 gload_lds for tile k+1 into
//   buf (k+1)&1; barrier; lgkmcnt(0); setprio(1) 16 MFMA setprio(0);
//   vmcnt(0); barrier.
// WAR: buf (k+1)&1 was last ds_read at tile k-1; every wave drained those
// reads (its lgkmcnt(0)) before the end-of-(k-1) barrier, and the prefetch
// is issued after that barrier. RAW: each wave's vmcnt(0) (gload_lds counts
// in the issuing wave's vmcnt) precedes the end-of-k barrier, which
// precedes tile k+1's ds_reads. vmcnt(0) is issued ~1 full K-tile after
// the loads (satisfied-on-arrival); residual stall hidden by the other block.
//
// LDS swizzle: row stride is 64 B (4 x 16 B chunks). Un-swizzled, fragment
// reads are 4-way bank conflicts. Chunk ^= (row>>1)&3 spreads each 8-lane
// issue group across all 8 16B-granules (verified conflict-free: round-1
// SQ_LDS_BANK_CONFLICT = 0 with the same scheme). gload_lds forces a linear
// LDS dest, so the permutation is applied to the *global source* address
// (bijective within each row); reads apply the same XOR (cOff).
// B staging note: row 512+tid has the same swizzle chunk as row tid
// (512 = 0 mod 32), so one B pointer + constant 128*KDIM offset suffices.
__global__ __launch_bounds__(512, 4) void gemm_act(const __bf16* __restrict__ A,
                                                   const __bf16* __restrict__ Bm,
                                                   const float* __restrict__ bias,
                                                   __bf16* __restrict__ P) {
  __shared__ __align__(16) __bf16 As[2][128 * 32];
  __shared__ __align__(16) __bf16 Bs[2][256 * 32];

  const int tid  = threadIdx.x;
  const int lane = tid & 63;
  const int wave = tid >> 6;       // 0..7
  const int quad = lane >> 4;      // 0..3
  const int lr   = lane & 15;      // row-in-16 (A/m), col-in-16 (B/n, C col)
  const int wr   = wave >> 2;      // 0..1  -> 64-row half of 128
  const int wc   = wave & 3;       // 0..3  -> 64-col slice of 256
  const int cOff = ((quad ^ ((lr >> 1) & 3)) << 3);  // swizzled chunk elem offset

  // Bijective XCD swizzle: nwg = 2560 = 8*320. Within an XCD, consecutive
  // blocks walk tile_m at (mostly) fixed tile_n -> B-panels L2-resident.
  const int nb  = blockIdx.x;
  const int sw  = (nb & 7) * 320 + (nb >> 3);
  const int tm  = sw & 127;         // 128 row tiles
  const int tn  = sw >> 7;          // 20 col tiles
  const int row0 = tm << 7;
  const int col0 = tn << 8;

  // Per-thread staging: 1 A chunk + 2 B chunks per tile (chunk = 16 B).
  // LDS slot c -> (row c>>2, slot c&3); source chunk = (c&3) ^ ((c>>3)&3).
  const int swz = (((tid & 3) ^ ((tid >> 3) & 3)) << 3);
  const __bf16* srcA = A  + (size_t)(row0 + (tid >> 2)) * KDIM + swz;
  const __bf16* srcB = Bm + (size_t)(col0 + (tid >> 2)) * KDIM + swz;
  const size_t bOff2 = (size_t)128 * KDIM;   // second B chunk: row +128, same swizzle

  f32x4 acc[4][4] = {};

  // Prologue: stage tile 0.
  async16(srcA,         As[0] + (size_t)tid * 8);
  async16(srcB,         Bs[0] + (size_t)tid * 8);
  async16(srcB + bOff2, Bs[0] + (size_t)tid * 8 + 4096);
  asm volatile("s_waitcnt vmcnt(0)" ::: "memory");
  asm volatile("s_barrier" ::: "memory");

  const int NT = KDIM / 32;  // 64 K-tiles
  for (int k = 0; k < NT; ++k) {
    const __bf16* ab = As[k & 1];
    const __bf16* bb = Bs[k & 1];
    const bool pf = (k + 1) < NT;

    bf16x8 af[4], bf[4];
#pragma unroll
    for (int i = 0; i < 4; ++i)
      af[i] = *(const bf16x8*)(ab + (wr * 64 + i * 16 + lr) * 32 + cOff);
#pragma unroll
    for (int j = 0; j < 4; ++j)
      bf[j] = *(const bf16x8*)(bb + (wc * 64 + j * 16 + lr) * 32 + cOff);

    if (pf) {  // prefetch tile k+1 into the buffer freed at tile k-1
      const int kc = (k + 1) * 32;
      __bf16* da = As[(k + 1) & 1];
      __bf16* db = Bs[(k + 1) & 1];
      async16(srcA + kc,         da + (size_t)tid * 8);
      async16(srcB + kc,         db + (size_t)tid * 8);
      async16(srcB + bOff2 + kc, db + (size_t)tid * 8 + 4096);
    }

    asm volatile("s_barrier" ::: "memory");
    asm volatile("s_waitcnt lgkmcnt(0)" ::: "memory");
    __builtin_amdgcn_s_setprio(1);
#pragma unroll
    for (int i = 0; i < 4; ++i)
#pragma unroll
      for (int j = 0; j < 4; ++j)
        acc[i][j] =
            __builtin_amdgcn_mfma_f32_16x16x32_bf16(af[i], bf[j], acc[i][j], 0, 0, 0);
    __builtin_amdgcn_s_setprio(0);

    if (pf) {
      // tile k+1's loads must have landed before its ds_reads next iter
      asm volatile("s_waitcnt vmcnt(0)" ::: "memory");
    }
    asm volatile("s_barrier" ::: "memory");
  }

  // Epilogue. C/D layout (m89/m91 verified): col = lane&15, row = quad*4 + reg.
  const int gate = col0 >> 10;  // 256-col tile never crosses a gate boundary
#pragma unroll
  for (int i = 0; i < 4; ++i) {
    const int grow = row0 + wr * 64 + i * 16 + quad * 4;
#pragma unroll
    for (int j = 0; j < 4; ++j) {
      const int gcol = col0 + wc * 64 + j * 16 + lr;
      const float bv = bias[gcol];
#pragma unroll
      for (int r = 0; r < 4; ++r) {
        const float v = acc[i][j][r] + bv;
        const float a = (gate == 3) ? fast_tanh(v) : fast_sigmoid(v);
        P[(size_t)(grow + r) * NDIM + gcol] = (__bf16)a;
      }
    }
  }
}

// ---------- phase 3: cell update + per-row fraction + outputs ----------
// one block per row; 256 threads x 4 consecutive cols each, vectorized
// bf16x4 / float4 loads (8-16 B/lane -> coalesced; G13).
__global__ __launch_bounds__(256) void fuse_out(const __bf16* __restrict__ P,
                                                const float* __restrict__ cprev,
                                                float* __restrict__ h_out,
                                                float* __restrict__ c_out) {
  const int r = blockIdx.x;
  const int t = threadIdx.x;
  const __bf16* Pr = P + (size_t)r * NDIM;
  const float* cpr = cprev + (size_t)r * HDIM;
  const int c0 = t * 4;

  const bf16x4 iv = *(const bf16x4*)(Pr + c0);
  const bf16x4 fv = *(const bf16x4*)(Pr + HDIM + c0);
  const bf16x4 ov = *(const bf16x4*)(Pr + 2 * HDIM + c0);
  const bf16x4 ch = *(const bf16x4*)(Pr + 3 * HDIM + c0);
  const bf16x4 gv = *(const bf16x4*)(Pr + 4 * HDIM + c0);
  const float4 cp4 = *(const float4*)(cpr + c0);
  const float cp[4] = {cp4.x, cp4.y, cp4.z, cp4.w};

  float ct[4];
  float num = 0.f, den = 0.f;
#pragma unroll
  for (int q = 0; q < 4; ++q) {
    ct[q] = (float)iv[q] * (float)ch[q] + (float)fv[q] * cp[q];
    num += ct[q] * cp[q];
    den += cp[q] * cp[q];
  }
  // wave (64-lane) shuffle reduce, then cross-wave via LDS
#pragma unroll
  for (int off = 32; off > 0; off >>= 1) {
    num += __shfl_down(num, off);
    den += __shfl_down(den, off);
  }
  __shared__ float sn[4], sd[4];
  const int lane = t & 63, wave = t >> 6;
  if (lane == 0) { sn[wave] = num; sd[wave] = den; }
  __syncthreads();
  const float frac = (sn[0] + sn[1] + sn[2] + sn[3]) /
                     (sd[0] + sd[1] + sd[2] + sd[3]);

  float4 ho, co;
  float hv[4];
#pragma unroll
  for (int q = 0; q < 4; ++q) {
    const float cd = ct[q] - (float)gv[q] * frac * cp[q];
    hv[q] = (float)ov[q] * fast_tanh(cd);
  }
  ho.x = hv[0]; ho.y = hv[1]; ho.z = hv[2]; ho.w = hv[3];
  co.x = ct[0]; co.y = ct[1]; co.z = ct[2]; co.w = ct[3];
  *(float4*)(h_out + (size_t)r * HDIM + c0) = ho;
  *(float4*)(c_out + (size_t)r * HDIM + c0) = co;
}

extern "C" void kernel_launch(void* const* d_in, const int* in_sizes, int n_in,
                              void* d_out, int out_size, void* d_ws, size_t ws_size,
                              hipStream_t stream) {
  const float* d_t    = (const float*)d_in[0];
  const float* h_prev = (const float*)d_in[1];
  const float* c_prev = (const float*)d_in[2];
  GatePtrs gp;
  for (int g = 0; g < 5; ++g) {
    gp.W[g] = (const float*)d_in[3 + g * 3];
    gp.b[g] = (const float*)d_in[4 + g * 3];
    gp.U[g] = (const float*)d_in[5 + g * 3];
  }

  char* ws = (char*)d_ws;
  __bf16* Apack  = (__bf16*)ws;
  __bf16* Bpack  = (__bf16*)(ws + WS_OFF_B);
  float*  biasA  = (float*)(ws + WS_OFF_BIAS);
  __bf16* P      = (__bf16*)(ws + WS_OFF_P);

  float* h_out = (float*)d_out;
  float* c_out = h_out + (size_t)B_ROWS * HDIM;

  pack_A<<<dim3(B_ROWS * (KDIM / 2048)), 256, 0, stream>>>(d_t, h_prev, Apack);           // 16384 blocks
  pack_B<<<dim3(NDIM), 256, 0, stream>>>(gp, Bpack);                                      // 5120 blocks
  pack_bias<<<dim3(NDIM / 256), 256, 0, stream>>>(gp, biasA);                             // 20 blocks
  gemm_act<<<dim3((B_ROWS / 128) * (NDIM / 256)), 512, 0, stream>>>(Apack, Bpack, biasA, P); // 2560 blocks
  fuse_out<<<dim3(B_ROWS), 256, 0, stream>>>(P, c_prev, h_out, c_out);                    // 16384 blocks
}